// Round 7
// baseline (11.075 us; speedup 1.0000x reference)
//
#include <hip/hip_runtime.h>

#define N_QUERIES 2097152

typedef float fx4 __attribute__((ext_vector_type(4)));

// Block = 256 threads, 512 queries (2 q/thread). 4096 blocks -> 2 resident
// generations per CU: gen-2 loads overlap gen-1 compute+stores, keeping HBM
// busy through the compute bubble that bounded the one-generation R6 kernel.
__device__ __forceinline__ float4 nearest_col(float qx, float qy,
                                              const float* __restrict__ sp)
{
    // nearest 2x2 cell-center block; jitter margin (0.1179 vs 0.0955) proves
    // the global argmin over all 64 jittered sites lies in this block.
    float fx = qx * 8.0f - 0.5f;
    float fy = qy * 8.0f - 0.5f;
    float fi = fminf(fmaxf(floorf(fx), 0.0f), 6.0f);
    float fj = fminf(fmaxf(floorf(fy), 0.0f), 6.0f);
    int k0 = (int)fi * 8 + (int)fj;

    const float* base = sp + k0;
    // candidates k0, k0+1, k0+8, k0+9 — ascending k + strict '<' matches
    // np.argmin tie-break; __fmul_rn/__fadd_rn match numpy (no FMA).
    float pxa = base[0],  pxb = base[1],  pxc = base[8],  pxd = base[9];
    float pya = base[64], pyb = base[65], pyc = base[72], pyd = base[73];

    float dx, dy, d2, best;
    int bk = k0;
    dx = qx - pxa; dy = qy - pya;
    best = __fadd_rn(__fmul_rn(dx, dx), __fmul_rn(dy, dy));
    dx = qx - pxb; dy = qy - pyb;
    d2 = __fadd_rn(__fmul_rn(dx, dx), __fmul_rn(dy, dy));
    if (d2 < best) { best = d2; bk = k0 + 1; }
    dx = qx - pxc; dy = qy - pyc;
    d2 = __fadd_rn(__fmul_rn(dx, dx), __fmul_rn(dy, dy));
    if (d2 < best) { best = d2; bk = k0 + 8; }
    dx = qx - pxd; dy = qy - pyd;
    d2 = __fadd_rn(__fmul_rn(dx, dx), __fmul_rn(dy, dy));
    if (d2 < best) { best = d2; bk = k0 + 9; }

    return make_float4(sp[128 + bk], sp[192 + bk], sp[256 + bk], 0.0f);
}

__global__ __launch_bounds__(256) void voronoi_kernel(
    const float* __restrict__ x,
    const float* __restrict__ p,
    float* __restrict__ out)
{
    __shared__ float sp[320];    // px[64] py[64] r[64] g[64] b[64] (SoA b32)
    __shared__ float oc[1536];   // 6 KB output staging (512 queries x 3)

    const int tid = threadIdx.x;
    if (tid < 64) {
        sp[tid]       = p[tid * 5 + 0];
        sp[64 + tid]  = p[tid * 5 + 1];
        sp[128 + tid] = p[tid * 5 + 2];
        sp[192 + tid] = p[tid * 5 + 3];
        sp[256 + tid] = p[tid * 5 + 4];
    }
    __syncthreads();

    // coalesced load: one lane-consecutive float4 (queries 2t, 2t+1)
    const float4* __restrict__ x4 = (const float4*)x + (size_t)blockIdx.x * 256;
    float4 a = x4[tid];

    float4 c0 = nearest_col(a.x, a.y, sp);
    float4 c1 = nearest_col(a.z, a.w, sp);

    // stage output tile in LDS
    float* o0 = &oc[6 * tid];
    o0[0] = c0.x; o0[1] = c0.y; o0[2] = c0.z;
    o0[3] = c1.x; o0[4] = c1.y; o0[5] = c1.z;
    __syncthreads();

    // coalesced nontemporal stores: 384 float4 per block
    fx4* __restrict__ o4 = (fx4*)out + (size_t)blockIdx.x * 384;
    const fx4* __restrict__ ocv = (const fx4*)oc;
    __builtin_nontemporal_store(ocv[tid], &o4[tid]);
    if (tid < 128)
        __builtin_nontemporal_store(ocv[256 + tid], &o4[256 + tid]);
}

extern "C" void kernel_launch(void* const* d_in, const int* in_sizes, int n_in,
                              void* d_out, int out_size, void* d_ws, size_t ws_size,
                              hipStream_t stream) {
    const float* x = (const float*)d_in[0];
    const float* p = (const float*)d_in[1];
    float* out = (float*)d_out;

    const int block = 256;
    const int grid = N_QUERIES / 512;   // 4096 blocks -> 2 generations/CU
    voronoi_kernel<<<grid, block, 0, stream>>>(x, p, out);
}

// Round 9
// 10.558 us; speedup vs baseline: 1.0490x; 1.0490x over previous
//
#include <hip/hip_runtime.h>

#define N_QUERIES 2097152

typedef float fx4 __attribute__((ext_vector_type(4)));

// Per query: 2x b128 position-pair gathers + 1x b128 color gather.
__device__ __forceinline__ fx4 nearest_col(float qx, float qy,
                                           const fx4* pr, const fx4* cl)
{
    // nearest 2x2 cell-center block; jitter margin (0.1179 vs 0.0955) proves
    // the global argmin over all 64 jittered sites lies in this block.
    float fx = qx * 8.0f - 0.5f;
    float fy = qy * 8.0f - 0.5f;
    float fi = fminf(fmaxf(floorf(fx), 0.0f), 6.0f);
    float fj = fminf(fmaxf(floorf(fy), 0.0f), 6.0f);
    int k0 = (int)fi * 8 + (int)fj;

    fx4 r0 = pr[k0];       // {px[k0],py[k0],px[k0+1],py[k0+1]}
    fx4 r1 = pr[k0 + 8];   // {px[k0+8],py[k0+8],px[k0+9],py[k0+9]}

    // ascending k + strict '<' == np.argmin tie-break;
    // __fmul_rn/__fadd_rn match numpy's separate roundings (no FMA).
    float dx, dy, d2, best;
    int bk = k0;
    dx = qx - r0.x; dy = qy - r0.y;
    best = __fadd_rn(__fmul_rn(dx, dx), __fmul_rn(dy, dy));
    dx = qx - r0.z; dy = qy - r0.w;
    d2 = __fadd_rn(__fmul_rn(dx, dx), __fmul_rn(dy, dy));
    if (d2 < best) { best = d2; bk = k0 + 1; }
    dx = qx - r1.x; dy = qy - r1.y;
    d2 = __fadd_rn(__fmul_rn(dx, dx), __fmul_rn(dy, dy));
    if (d2 < best) { best = d2; bk = k0 + 8; }
    dx = qx - r1.z; dy = qy - r1.w;
    d2 = __fadd_rn(__fmul_rn(dx, dx), __fmul_rn(dy, dy));
    if (d2 < best) { best = d2; bk = k0 + 9; }

    return cl[bk];
}

__global__ __launch_bounds__(256) void voronoi_kernel(
    const float* __restrict__ x,
    const float* __restrict__ p,
    float* __restrict__ out)
{
    __shared__ fx4 pairs[64];     // shared site tables (read-only after build)
    __shared__ fx4 cols [64];
    __shared__ fx4 oc[4][192];    // per-wave output staging (256 q x 3 floats)

    const int tid  = threadIdx.x;
    const int wid  = tid >> 6;
    const int lane = tid & 63;

    // wave-contiguous queries: wave wid owns block-rel queries [256wid, 256wid+256)
    const fx4* __restrict__ x4 =
        (const fx4*)x + (size_t)blockIdx.x * 512 + wid * 128;
    fx4 a = x4[lane];         // queries 256wid + 2L, 2L+1
    fx4 b = x4[64 + lane];    // queries 256wid + 128 + 2L, +1

    if (tid < 64) {
        const float* ps = p + tid * 5;
        int nb = ((tid & 7) == 7) ? tid : tid + 1;   // col+1 neighbor (col=7 never read)
        const float* pn = p + nb * 5;
        pairs[tid] = fx4{ps[0], ps[1], pn[0], pn[1]};
        cols [tid] = fx4{ps[2], ps[3], ps[4], 0.0f};
    }
    __syncthreads();   // tables ready; waves decouple after this

    fx4 c0 = nearest_col(a.x, a.y, pairs, cols);
    fx4 c1 = nearest_col(a.z, a.w, pairs, cols);
    fx4 c2 = nearest_col(b.x, b.y, pairs, cols);
    fx4 c3 = nearest_col(b.z, b.w, pairs, cols);

    // stage: lane L -> wave-rel floats [6L,6L+6) and [384+6L,384+6L+6)
    float* o0 = (float*)&oc[wid][0] + 6 * lane;
    o0[0] = c0.x; o0[1] = c0.y; o0[2] = c0.z;
    o0[3] = c1.x; o0[4] = c1.y; o0[5] = c1.z;
    float* o1 = (float*)&oc[wid][0] + 384 + 6 * lane;
    o1[0] = c2.x; o1[1] = c2.y; o1[2] = c2.z;
    o1[3] = c3.x; o1[4] = c3.y; o1[5] = c3.z;

    // within-wave RAW: HW DS pipe is in-order per wave; fence the compiler
    asm volatile("s_waitcnt lgkmcnt(0)" ::: "memory");
    __builtin_amdgcn_sched_barrier(0);

    // readback unit-stride, store nontemporal (no block barrier)
    const fx4* ocv = oc[wid];
    fx4* __restrict__ o4 = (fx4*)out + (size_t)blockIdx.x * 768 + wid * 192;
    __builtin_nontemporal_store(ocv[lane],        &o4[lane]);
    __builtin_nontemporal_store(ocv[64 + lane],   &o4[64 + lane]);
    __builtin_nontemporal_store(ocv[128 + lane],  &o4[128 + lane]);
}

extern "C" void kernel_launch(void* const* d_in, const int* in_sizes, int n_in,
                              void* d_out, int out_size, void* d_ws, size_t ws_size,
                              hipStream_t stream) {
    const float* x = (const float*)d_in[0];
    const float* p = (const float*)d_in[1];
    float* out = (float*)d_out;

    const int block = 256;
    const int grid = N_QUERIES / 1024;   // 2048 blocks -> 8/CU, 32 waves/CU
    voronoi_kernel<<<grid, block, 0, stream>>>(x, p, out);
}